// Round 3
// baseline (2990.720 us; speedup 1.0000x reference)
//
#include <hip/hip_runtime.h>
#include <float.h>

typedef _Float16 f16;
typedef f16 f16x8 __attribute__((ext_vector_type(8)));
typedef float f32x4 __attribute__((ext_vector_type(4)));
typedef unsigned int u32;

#define NPTS 262144
#define DDIM 128
#define NVQ 6
#define KCODES 512
#define TM 64          // points per block
#define BLOCKT 256
#define CHUNKC 64      // codes staged per LDS chunk
#define NCHUNK (KCODES / CHUNKC)

// swizzled element index for f16 [rows][128] tiles, 16B-group granularity.
__device__ __forceinline__ int swz(int row, int grp) {
    return row * DDIM + ((grp ^ (row & 7)) << 3);
}

__device__ __forceinline__ f16x8 cvt8(float4 a, float4 b) {
    f16x8 h;
    h[0] = (f16)a.x; h[1] = (f16)a.y; h[2] = (f16)a.z; h[3] = (f16)a.w;
    h[4] = (f16)b.x; h[5] = (f16)b.y; h[6] = (f16)b.z; h[7] = (f16)b.w;
    return h;
}

// ---------------------------------------------------------------------------
__global__ void zero_commit_kernel(float* p) { *p = 0.0f; }

__global__ void norms_kernel(const float* __restrict__ cb, float* __restrict__ norms) {
    int row = blockIdx.x;
    int lane = threadIdx.x;
    const float* r = cb + (size_t)row * DDIM;
    float2 v = *(const float2*)(r + lane * 2);
    float s = v.x * v.x + v.y * v.y;
    #pragma unroll
    for (int m = 32; m >= 1; m >>= 1) s += __shfl_xor(s, m);
    if (lane == 0) norms[row] = s;
}

__global__ void preconv_kernel(const float* __restrict__ cb, f16* __restrict__ cb16) {
    size_t base = ((size_t)blockIdx.x * 256 + threadIdx.x) * 8;
    float4 a = *(const float4*)(cb + base);
    float4 b = *(const float4*)(cb + base + 4);
    *(f16x8*)(cb16 + base) = cvt8(a, b);
}

// ---------------------------------------------------------------------------
// Fused residual-VQ (6 stages, MFMA fp16 scoring + fp32 top-2 rescue) + linear.
// score = dot - 0.5*||E||^2 folded into MFMA acc init; argmax.
template<bool PRE>
__global__ __launch_bounds__(BLOCKT, 4)
void rvq_kernel(const float* __restrict__ x, const float* __restrict__ cb,
                const f16* __restrict__ cb16, const float* __restrict__ W,
                const float* __restrict__ bias, const float* __restrict__ norms,
                float* __restrict__ out) {
    __shared__ f16   rh[TM * DDIM];          // residual (or y) fp16, swizzled  (16 KB)
    __shared__ f16   e_lds[CHUNKC * DDIM];   // code chunk / W fp16, swizzled   (16 KB)
    __shared__ float cn[CHUNKC];             // code norms / bias               (256 B)
    __shared__ uint4 cand[4 * TM];           // per-wave top2; reused as scratch (4 KB)
    __shared__ uint2 besti2[TM];             // (512 B)

    const int tid  = threadIdx.x;
    const int wid  = tid >> 6;
    const int lane = tid & 63;
    const int g    = lane >> 4;      // k-group 0..3
    const int li   = lane & 15;      // row/col within 16-tile
    const int p_own = tid >> 2;      // owned point 0..63
    const int q     = tid & 3;       // owned d-quarter
    const int p0    = blockIdx.x * TM;

    // ---- load x quarter into registers ----
    float r[32];
    {
        const float* xs = x + (size_t)(p0 + p_own) * DDIM + q * 32;
        #pragma unroll
        for (int k = 0; k < 8; ++k) {
            float4 v = *(const float4*)(xs + 4 * k);
            r[4*k] = v.x; r[4*k+1] = v.y; r[4*k+2] = v.z; r[4*k+3] = v.w;
        }
    }
    #pragma unroll
    for (int k = 0; k < 4; ++k) {
        f16x8 h;
        #pragma unroll
        for (int m = 0; m < 8; ++m) h[m] = (f16)r[8*k+m];
        *(f16x8*)&rh[swz(p_own, q * 4 + k)] = h;
    }
    __syncthreads();

    float commit_part = 0.0f;

    for (int s = 0; s < NVQ; ++s) {
        // ---- B-fragments: residual fp16 in registers, reused over all codes ----
        f16x8 Bf[4][4];   // [point-tile j][ks]
        #pragma unroll
        for (int j = 0; j < 4; ++j)
            #pragma unroll
            for (int ks = 0; ks < 4; ++ks)
                Bf[j][ks] = *(const f16x8*)&rh[swz(16 * j + li, ks * 4 + g)];

        float s1[4], s2[4]; u32 i1[4], i2[4];
        #pragma unroll
        for (int j = 0; j < 4; ++j) { s1[j] = -FLT_MAX; s2[j] = -FLT_MAX; i1[j] = 0xffffffffu; i2[j] = 0xffffffffu; }

        for (int ch = 0; ch < NCHUNK; ++ch) {
            __syncthreads();
            // ---- stage 64-code chunk into e_lds (fp16, swizzled) ----
            if (PRE) {
                const f16* src = cb16 + (size_t)(s * KCODES + ch * CHUNKC) * DDIM;
                #pragma unroll
                for (int it = 0; it < 4; ++it) {
                    int u = tid + it * BLOCKT; int row = u >> 4, grp = u & 15;
                    int4 v = *(const int4*)(src + row * DDIM + grp * 8);
                    *(int4*)&e_lds[swz(row, grp)] = v;
                }
            } else {
                const float* src = cb + (size_t)(s * KCODES + ch * CHUNKC) * DDIM;
                #pragma unroll
                for (int it = 0; it < 4; ++it) {
                    int u = tid + it * BLOCKT; int row = u >> 4, grp = u & 15;
                    const float* sp = src + row * DDIM + grp * 8;
                    float4 a = *(const float4*)sp;
                    float4 b = *(const float4*)(sp + 4);
                    *(f16x8*)&e_lds[swz(row, grp)] = cvt8(a, b);
                }
            }
            if (tid < CHUNKC) cn[tid] = norms[s * KCODES + ch * CHUNKC + tid];
            __syncthreads();

            // ---- acc init = -0.5*||E||^2 (C layout: row=code=(g*4+reg)) ----
            float4 nv = *(const float4*)&cn[16 * wid + 4 * g];
            f32x4 ainit;
            ainit[0] = -0.5f * nv.x; ainit[1] = -0.5f * nv.y;
            ainit[2] = -0.5f * nv.z; ainit[3] = -0.5f * nv.w;
            f32x4 acc[4];
            #pragma unroll
            for (int j = 0; j < 4; ++j) acc[j] = ainit;

            // ---- MFMA: D[code][point], wave wid handles rows 16*wid..+15 ----
            #pragma unroll
            for (int ks = 0; ks < 4; ++ks) {
                f16x8 A = *(const f16x8*)&e_lds[swz(16 * wid + li, ks * 4 + g)];
                #pragma unroll
                for (int j = 0; j < 4; ++j)
                    acc[j] = __builtin_amdgcn_mfma_f32_16x16x32_f16(A, Bf[j][ks], acc[j], 0, 0, 0);
            }

            // ---- top-2 insertion; within-lane indices ascend -> strict > only ----
            u32 cbase = (u32)(ch * CHUNKC + 16 * wid + 4 * g);
            u32 cc0 = cbase, cc1 = cbase + 1, cc2r = cbase + 2, cc3 = cbase + 3;
            #pragma unroll
            for (int j = 0; j < 4; ++j) {
                #pragma unroll
                for (int reg = 0; reg < 4; ++reg) {
                    float sc = acc[j][reg];
                    u32 cc = (reg == 0) ? cc0 : (reg == 1) ? cc1 : (reg == 2) ? cc2r : cc3;
                    bool gt1 = sc > s1[j];
                    bool gt2 = sc > s2[j];
                    s2[j] = gt1 ? s1[j] : (gt2 ? sc : s2[j]);
                    i2[j] = gt1 ? i1[j] : (gt2 ? cc : i2[j]);
                    s1[j] = gt1 ? sc : s1[j];
                    i1[j] = gt1 ? cc : i1[j];
                }
            }
        }

        // ---- in-wave merge across k-groups (lanes xor 16, 32); max, tie->low idx ----
        #pragma unroll
        for (int m = 16; m <= 32; m <<= 1) {
            #pragma unroll
            for (int j = 0; j < 4; ++j) {
                float b1 = __shfl_xor(s1[j], m); u32 bi1 = (u32)__shfl_xor((int)i1[j], m);
                float b2 = __shfl_xor(s2[j], m); u32 bi2 = (u32)__shfl_xor((int)i2[j], m);
                bool bf = (b1 > s1[j]) || (b1 == s1[j] && bi1 < i1[j]);
                float w1d = bf ? b1 : s1[j]; u32 w1i = bf ? bi1 : i1[j];
                float l1d = bf ? s1[j] : b1; u32 l1i = bf ? i1[j] : bi1;
                float s2d = bf ? b2 : s2[j]; u32 s2i = bf ? bi2 : i2[j];
                bool sf = (s2d > l1d) || (s2d == l1d && s2i < l1i);
                s1[j] = w1d; i1[j] = w1i;
                s2[j] = sf ? s2d : l1d; i2[j] = sf ? s2i : l1i;
            }
        }
        if (lane < 16) {
            #pragma unroll
            for (int j = 0; j < 4; ++j)
                cand[wid * TM + 16 * j + li] = make_uint4(__float_as_uint(s1[j]), i1[j],
                                                          __float_as_uint(s2[j]), i2[j]);
        }
        __syncthreads();

        // ---- cross-wave merge (each wave saw 1/4 of the codes) ----
        if (tid < TM) {
            float m1d = -FLT_MAX, m2d = -FLT_MAX; u32 m1i = 0xffffffffu, m2i = 0xffffffffu;
            #pragma unroll
            for (int w = 0; w < 4; ++w) {
                uint4 v = cand[w * TM + tid];
                float a1 = __uint_as_float(v.x); u32 ai1 = v.y;
                float a2 = __uint_as_float(v.z); u32 ai2 = v.w;
                bool bf = (a1 > m1d) || (a1 == m1d && ai1 < m1i);
                float w1d = bf ? a1 : m1d; u32 w1i = bf ? ai1 : m1i;
                float l1d = bf ? m1d : a1; u32 l1i = bf ? m1i : ai1;
                float s2d = bf ? a2 : m2d; u32 s2i = bf ? ai2 : m2i;
                bool sf = (s2d > l1d) || (s2d == l1d && s2i < l1i);
                m1d = w1d; m1i = w1i;
                m2d = sf ? s2d : l1d; m2i = sf ? s2i : l1i;
            }
            besti2[tid] = make_uint2(m1i, m2i);
        }
        __syncthreads();

        // ---- exact fp32 rescue: recompute both candidates, pick lex-min dist ----
        uint2 cc2v = besti2[p_own];
        int c1 = (int)cc2v.x, c2 = (int)cc2v.y;
        const float* E1 = cb + (size_t)(s * KCODES + c1) * DDIM + q * 32;
        const float* E2 = cb + (size_t)(s * KCODES + c2) * DDIM + q * 32;
        float dot1 = 0.0f, dot2 = 0.0f;
        #pragma unroll
        for (int k = 0; k < 8; ++k) {
            float4 a = *(const float4*)(E1 + 4 * k);
            dot1 += a.x * r[4*k] + a.y * r[4*k+1] + a.z * r[4*k+2] + a.w * r[4*k+3];
        }
        #pragma unroll
        for (int k = 0; k < 8; ++k) {
            float4 a = *(const float4*)(E2 + 4 * k);
            dot2 += a.x * r[4*k] + a.y * r[4*k+1] + a.z * r[4*k+2] + a.w * r[4*k+3];
        }
        dot1 += __shfl_xor(dot1, 1); dot1 += __shfl_xor(dot1, 2);
        dot2 += __shfl_xor(dot2, 1); dot2 += __shfl_xor(dot2, 2);
        float d1e = fmaf(-2.0f, dot1, norms[s * KCODES + c1]);
        float d2e = fmaf(-2.0f, dot2, norms[s * KCODES + c2]);
        int best = (d2e < d1e || (d2e == d1e && c2 < c1)) ? c2 : c1;

        if (s == 0 && q == 0)
            out[(size_t)NPTS * DDIM + p0 + p_own] = (float)best;

        // ---- exact residual update from fp32 code row ----
        {
            const float* Eb = cb + (size_t)(s * KCODES + best) * DDIM + q * 32;
            float cp = 0.0f;
            #pragma unroll
            for (int k = 0; k < 8; ++k) {
                float4 a = *(const float4*)(Eb + 4 * k);
                r[4*k]   -= a.x; r[4*k+1] -= a.y; r[4*k+2] -= a.z; r[4*k+3] -= a.w;
                cp += r[4*k]*r[4*k] + r[4*k+1]*r[4*k+1] + r[4*k+2]*r[4*k+2] + r[4*k+3]*r[4*k+3];
            }
            if (s == 0) commit_part = cp;
        }

        __syncthreads();   // everyone done with cand/besti2 and B-frag reads
        // ---- rebuild rh: residual fp16 (or y = x - r after last stage) ----
        if (s < NVQ - 1) {
            #pragma unroll
            for (int k = 0; k < 4; ++k) {
                f16x8 h;
                #pragma unroll
                for (int m = 0; m < 8; ++m) h[m] = (f16)r[8*k+m];
                *(f16x8*)&rh[swz(p_own, q * 4 + k)] = h;
            }
        } else {
            const float* xs = x + (size_t)(p0 + p_own) * DDIM + q * 32;
            #pragma unroll
            for (int k = 0; k < 4; ++k) {
                float4 a = *(const float4*)(xs + 8 * k);
                float4 b = *(const float4*)(xs + 8 * k + 4);
                f16x8 h;
                h[0]=(f16)(a.x - r[8*k+0]); h[1]=(f16)(a.y - r[8*k+1]);
                h[2]=(f16)(a.z - r[8*k+2]); h[3]=(f16)(a.w - r[8*k+3]);
                h[4]=(f16)(b.x - r[8*k+4]); h[5]=(f16)(b.y - r[8*k+5]);
                h[6]=(f16)(b.z - r[8*k+6]); h[7]=(f16)(b.w - r[8*k+7]);
                *(f16x8*)&rh[swz(p_own, q * 4 + k)] = h;
            }
        }
        __syncthreads();
    }

    // ---- final linear: out = y @ W^T + b (A = W rows, 2 chunks of 64) ----
    {
        f16x8 Bf[4][4];
        #pragma unroll
        for (int j = 0; j < 4; ++j)
            #pragma unroll
            for (int ks = 0; ks < 4; ++ks)
                Bf[j][ks] = *(const f16x8*)&rh[swz(16 * j + li, ks * 4 + g)];

        for (int ch = 0; ch < 2; ++ch) {
            __syncthreads();
            {
                const float* src = W + (size_t)ch * CHUNKC * DDIM;
                #pragma unroll
                for (int it = 0; it < 4; ++it) {
                    int u = tid + it * BLOCKT; int row = u >> 4, grp = u & 15;
                    const float* sp = src + row * DDIM + grp * 8;
                    float4 a = *(const float4*)sp;
                    float4 b = *(const float4*)(sp + 4);
                    *(f16x8*)&e_lds[swz(row, grp)] = cvt8(a, b);
                }
                if (tid < CHUNKC) cn[tid] = bias[ch * CHUNKC + tid];
            }
            __syncthreads();

            float4 bn = *(const float4*)&cn[16 * wid + 4 * g];
            f32x4 acc[4];
            #pragma unroll
            for (int j = 0; j < 4; ++j) {
                acc[j][0] = bn.x; acc[j][1] = bn.y; acc[j][2] = bn.z; acc[j][3] = bn.w;
            }
            #pragma unroll
            for (int ks = 0; ks < 4; ++ks) {
                f16x8 A = *(const f16x8*)&e_lds[swz(16 * wid + li, ks * 4 + g)];
                #pragma unroll
                for (int j = 0; j < 4; ++j)
                    acc[j] = __builtin_amdgcn_mfma_f32_16x16x32_f16(A, Bf[j][ks], acc[j], 0, 0, 0);
            }

            int obase = ch * CHUNKC + 16 * wid + 4 * g;
            #pragma unroll
            for (int j = 0; j < 4; ++j) {
                int p = 16 * j + li;
                float4 o;
                o.x = acc[j][0]; o.y = acc[j][1]; o.z = acc[j][2]; o.w = acc[j][3];
                *(float4*)(out + (size_t)(p0 + p) * DDIM + obase) = o;
            }
        }
    }

    // ---- commit loss: wave shuffle-reduce, then 4 partials + atomic ----
    {
        float cp = commit_part;
        #pragma unroll
        for (int m = 1; m <= 32; m <<= 1) cp += __shfl_xor(cp, m);
        __syncthreads();                 // cand free for reuse as scratch
        float* wsum = (float*)cand;
        if (lane == 0) wsum[wid] = cp;
        __syncthreads();
        if (tid == 0) {
            float t = (wsum[0] + wsum[1]) + (wsum[2] + wsum[3]);
            atomicAdd(out + (size_t)NPTS * DDIM + NPTS,
                      t * (1.0f / ((float)NPTS * (float)DDIM)));
        }
    }
}

// ---------------------------------------------------------------------------
extern "C" void kernel_launch(void* const* d_in, const int* in_sizes, int n_in,
                              void* d_out, int out_size, void* d_ws, size_t ws_size,
                              hipStream_t stream) {
    const float* x    = (const float*)d_in[0];
    const float* cb   = (const float*)d_in[1];
    const float* linw = (const float*)d_in[2];
    const float* linb = (const float*)d_in[3];
    float* out  = (float*)d_out;
    float* norms = (float*)d_ws;                       // 3072 floats
    f16*  cb16  = (f16*)((char*)d_ws + 16384);         // 786432 B fp16 codebook
    const size_t need = 16384 + (size_t)NVQ * KCODES * DDIM * 2;

    zero_commit_kernel<<<1, 1, 0, stream>>>(out + (size_t)NPTS * DDIM + NPTS);
    norms_kernel<<<NVQ * KCODES, 64, 0, stream>>>(cb, norms);

    if (ws_size >= need) {
        preconv_kernel<<<(NVQ * KCODES * DDIM) / (256 * 8), 256, 0, stream>>>(cb, cb16);
        rvq_kernel<true><<<NPTS / TM, BLOCKT, 0, stream>>>(x, cb, cb16, linw, linb, norms, out);
    } else {
        rvq_kernel<false><<<NPTS / TM, BLOCKT, 0, stream>>>(x, cb, cb16, linw, linb, norms, out);
    }
}

// Round 4
// 1302.122 us; speedup vs baseline: 2.2968x; 2.2968x over previous
//
#include <hip/hip_runtime.h>
#include <float.h>

typedef _Float16 f16;
typedef f16 f16x8 __attribute__((ext_vector_type(8)));
typedef float f32x4 __attribute__((ext_vector_type(4)));
typedef unsigned int u32;

#define NPTS 262144
#define DDIM 128
#define NVQ 6
#define KCODES 512
#define TM 64          // points per block
#define BLOCKT 256
#define CHUNKC 64      // codes staged per LDS chunk
#define NCHUNK (KCODES / CHUNKC)

// swizzled element index for f16 [rows][128] tiles, 16B-group granularity.
__device__ __forceinline__ int swz(int row, int grp) {
    return row * DDIM + ((grp ^ (row & 7)) << 3);
}

__device__ __forceinline__ f16x8 cvt8(float4 a, float4 b) {
    f16x8 h;
    h[0] = (f16)a.x; h[1] = (f16)a.y; h[2] = (f16)a.z; h[3] = (f16)a.w;
    h[4] = (f16)b.x; h[5] = (f16)b.y; h[6] = (f16)b.z; h[7] = (f16)b.w;
    return h;
}

// ---------------------------------------------------------------------------
__global__ void zero_commit_kernel(float* p) { *p = 0.0f; }

__global__ void norms_kernel(const float* __restrict__ cb, float* __restrict__ norms) {
    int row = blockIdx.x;
    int lane = threadIdx.x;
    const float* r = cb + (size_t)row * DDIM;
    float2 v = *(const float2*)(r + lane * 2);
    float s = v.x * v.x + v.y * v.y;
    #pragma unroll
    for (int m = 32; m >= 1; m >>= 1) s += __shfl_xor(s, m);
    if (lane == 0) norms[row] = s;
}

__global__ void preconv_kernel(const float* __restrict__ cb, f16* __restrict__ cb16) {
    size_t base = ((size_t)blockIdx.x * 256 + threadIdx.x) * 8;
    float4 a = *(const float4*)(cb + base);
    float4 b = *(const float4*)(cb + base + 4);
    *(f16x8*)(cb16 + base) = cvt8(a, b);
}

// ---------------------------------------------------------------------------
// Fused residual-VQ (6 stages, MFMA fp16 scoring + fp32 top-2 rescue) + linear.
// score = dot - 0.5*||E||^2 folded into MFMA acc init; argmax.
// __launch_bounds__(256,2): compiler allocates 128 VGPR (round-2 evidence);
// (256,4) forced 64 VGPR -> catastrophic scratch spill (round-3 post-mortem).
// Residency: LDS 37.9KB -> 4 blocks/CU; VGPR 128 -> 4 waves/SIMD -> 4 blocks/CU.
template<bool PRE>
__global__ __launch_bounds__(BLOCKT, 2)
void rvq_kernel(const float* __restrict__ x, const float* __restrict__ cb,
                const f16* __restrict__ cb16, const float* __restrict__ W,
                const float* __restrict__ bias, const float* __restrict__ norms,
                float* __restrict__ out) {
    __shared__ f16   rh[TM * DDIM];          // residual (or y) fp16, swizzled  (16 KB)
    __shared__ f16   e_lds[CHUNKC * DDIM];   // code chunk / W fp16, swizzled   (16 KB)
    __shared__ float cn[CHUNKC];             // code norms / bias               (256 B)
    __shared__ uint4 cand[4 * TM];           // per-wave top2; reused as scratch (4 KB)
    __shared__ uint2 besti2[TM];             // (512 B)

    const int tid  = threadIdx.x;
    const int wid  = tid >> 6;
    const int lane = tid & 63;
    const int g    = lane >> 4;      // k-group 0..3
    const int li   = lane & 15;      // row/col within 16-tile
    const int p_own = tid >> 2;      // owned point 0..63
    const int q     = tid & 3;       // owned d-quarter
    const int p0    = blockIdx.x * TM;

    // ---- load x quarter into registers ----
    float r[32];
    {
        const float* xs = x + (size_t)(p0 + p_own) * DDIM + q * 32;
        #pragma unroll
        for (int k = 0; k < 8; ++k) {
            float4 v = *(const float4*)(xs + 4 * k);
            r[4*k] = v.x; r[4*k+1] = v.y; r[4*k+2] = v.z; r[4*k+3] = v.w;
        }
    }
    #pragma unroll
    for (int k = 0; k < 4; ++k) {
        f16x8 h;
        #pragma unroll
        for (int m = 0; m < 8; ++m) h[m] = (f16)r[8*k+m];
        *(f16x8*)&rh[swz(p_own, q * 4 + k)] = h;
    }
    __syncthreads();

    float commit_part = 0.0f;

    for (int s = 0; s < NVQ; ++s) {
        // ---- B-fragments: residual fp16 in registers, reused over all codes ----
        f16x8 Bf[4][4];   // [point-tile j][ks]
        #pragma unroll
        for (int j = 0; j < 4; ++j)
            #pragma unroll
            for (int ks = 0; ks < 4; ++ks)
                Bf[j][ks] = *(const f16x8*)&rh[swz(16 * j + li, ks * 4 + g)];

        float s1[4], s2[4]; u32 i1[4], i2[4];
        #pragma unroll
        for (int j = 0; j < 4; ++j) { s1[j] = -FLT_MAX; s2[j] = -FLT_MAX; i1[j] = 0xffffffffu; i2[j] = 0xffffffffu; }

        for (int ch = 0; ch < NCHUNK; ++ch) {
            __syncthreads();
            // ---- stage 64-code chunk into e_lds (fp16, swizzled) ----
            if (PRE) {
                const f16* src = cb16 + (size_t)(s * KCODES + ch * CHUNKC) * DDIM;
                #pragma unroll
                for (int it = 0; it < 4; ++it) {
                    int u = tid + it * BLOCKT; int row = u >> 4, grp = u & 15;
                    int4 v = *(const int4*)(src + row * DDIM + grp * 8);
                    *(int4*)&e_lds[swz(row, grp)] = v;
                }
            } else {
                const float* src = cb + (size_t)(s * KCODES + ch * CHUNKC) * DDIM;
                #pragma unroll
                for (int it = 0; it < 4; ++it) {
                    int u = tid + it * BLOCKT; int row = u >> 4, grp = u & 15;
                    const float* sp = src + row * DDIM + grp * 8;
                    float4 a = *(const float4*)sp;
                    float4 b = *(const float4*)(sp + 4);
                    *(f16x8*)&e_lds[swz(row, grp)] = cvt8(a, b);
                }
            }
            if (tid < CHUNKC) cn[tid] = norms[s * KCODES + ch * CHUNKC + tid];
            __syncthreads();

            // ---- acc init = -0.5*||E||^2 (C layout: row=code=(g*4+reg)) ----
            float4 nv = *(const float4*)&cn[16 * wid + 4 * g];
            f32x4 ainit;
            ainit[0] = -0.5f * nv.x; ainit[1] = -0.5f * nv.y;
            ainit[2] = -0.5f * nv.z; ainit[3] = -0.5f * nv.w;
            f32x4 acc[4];
            #pragma unroll
            for (int j = 0; j < 4; ++j) acc[j] = ainit;

            // ---- MFMA: D[code][point], wave wid handles rows 16*wid..+15 ----
            #pragma unroll
            for (int ks = 0; ks < 4; ++ks) {
                f16x8 A = *(const f16x8*)&e_lds[swz(16 * wid + li, ks * 4 + g)];
                #pragma unroll
                for (int j = 0; j < 4; ++j)
                    acc[j] = __builtin_amdgcn_mfma_f32_16x16x32_f16(A, Bf[j][ks], acc[j], 0, 0, 0);
            }

            // ---- top-2 insertion; within-lane indices ascend -> strict > only ----
            u32 cbase = (u32)(ch * CHUNKC + 16 * wid + 4 * g);
            u32 cc0 = cbase, cc1 = cbase + 1, cc2r = cbase + 2, cc3 = cbase + 3;
            #pragma unroll
            for (int j = 0; j < 4; ++j) {
                #pragma unroll
                for (int reg = 0; reg < 4; ++reg) {
                    float sc = acc[j][reg];
                    u32 cc = (reg == 0) ? cc0 : (reg == 1) ? cc1 : (reg == 2) ? cc2r : cc3;
                    bool gt1 = sc > s1[j];
                    bool gt2 = sc > s2[j];
                    s2[j] = gt1 ? s1[j] : (gt2 ? sc : s2[j]);
                    i2[j] = gt1 ? i1[j] : (gt2 ? cc : i2[j]);
                    s1[j] = gt1 ? sc : s1[j];
                    i1[j] = gt1 ? cc : i1[j];
                }
            }
        }

        // ---- in-wave merge across k-groups (lanes xor 16, 32); max, tie->low idx ----
        #pragma unroll
        for (int m = 16; m <= 32; m <<= 1) {
            #pragma unroll
            for (int j = 0; j < 4; ++j) {
                float b1 = __shfl_xor(s1[j], m); u32 bi1 = (u32)__shfl_xor((int)i1[j], m);
                float b2 = __shfl_xor(s2[j], m); u32 bi2 = (u32)__shfl_xor((int)i2[j], m);
                bool bf = (b1 > s1[j]) || (b1 == s1[j] && bi1 < i1[j]);
                float w1d = bf ? b1 : s1[j]; u32 w1i = bf ? bi1 : i1[j];
                float l1d = bf ? s1[j] : b1; u32 l1i = bf ? i1[j] : bi1;
                float s2d = bf ? b2 : s2[j]; u32 s2i = bf ? bi2 : i2[j];
                bool sf = (s2d > l1d) || (s2d == l1d && s2i < l1i);
                s1[j] = w1d; i1[j] = w1i;
                s2[j] = sf ? s2d : l1d; i2[j] = sf ? s2i : l1i;
            }
        }
        if (lane < 16) {
            #pragma unroll
            for (int j = 0; j < 4; ++j)
                cand[wid * TM + 16 * j + li] = make_uint4(__float_as_uint(s1[j]), i1[j],
                                                          __float_as_uint(s2[j]), i2[j]);
        }
        __syncthreads();

        // ---- cross-wave merge (each wave saw 1/4 of the codes) ----
        if (tid < TM) {
            float m1d = -FLT_MAX, m2d = -FLT_MAX; u32 m1i = 0xffffffffu, m2i = 0xffffffffu;
            #pragma unroll
            for (int w = 0; w < 4; ++w) {
                uint4 v = cand[w * TM + tid];
                float a1 = __uint_as_float(v.x); u32 ai1 = v.y;
                float a2 = __uint_as_float(v.z); u32 ai2 = v.w;
                bool bf = (a1 > m1d) || (a1 == m1d && ai1 < m1i);
                float w1d = bf ? a1 : m1d; u32 w1i = bf ? ai1 : m1i;
                float l1d = bf ? m1d : a1; u32 l1i = bf ? m1i : ai1;
                float s2d = bf ? a2 : m2d; u32 s2i = bf ? ai2 : m2i;
                bool sf = (s2d > l1d) || (s2d == l1d && s2i < l1i);
                m1d = w1d; m1i = w1i;
                m2d = sf ? s2d : l1d; m2i = sf ? s2i : l1i;
            }
            besti2[tid] = make_uint2(m1i, m2i);
        }
        __syncthreads();

        // ---- exact fp32 rescue: recompute both candidates, pick lex-min dist ----
        uint2 cc2v = besti2[p_own];
        int c1 = (int)cc2v.x, c2 = (int)cc2v.y;
        const float* E1 = cb + (size_t)(s * KCODES + c1) * DDIM + q * 32;
        const float* E2 = cb + (size_t)(s * KCODES + c2) * DDIM + q * 32;
        float dot1 = 0.0f, dot2 = 0.0f;
        #pragma unroll
        for (int k = 0; k < 8; ++k) {
            float4 a = *(const float4*)(E1 + 4 * k);
            dot1 += a.x * r[4*k] + a.y * r[4*k+1] + a.z * r[4*k+2] + a.w * r[4*k+3];
        }
        #pragma unroll
        for (int k = 0; k < 8; ++k) {
            float4 a = *(const float4*)(E2 + 4 * k);
            dot2 += a.x * r[4*k] + a.y * r[4*k+1] + a.z * r[4*k+2] + a.w * r[4*k+3];
        }
        dot1 += __shfl_xor(dot1, 1); dot1 += __shfl_xor(dot1, 2);
        dot2 += __shfl_xor(dot2, 1); dot2 += __shfl_xor(dot2, 2);
        float d1e = fmaf(-2.0f, dot1, norms[s * KCODES + c1]);
        float d2e = fmaf(-2.0f, dot2, norms[s * KCODES + c2]);
        int best = (d2e < d1e || (d2e == d1e && c2 < c1)) ? c2 : c1;

        if (s == 0 && q == 0)
            out[(size_t)NPTS * DDIM + p0 + p_own] = (float)best;

        // ---- exact residual update from fp32 code row ----
        {
            const float* Eb = cb + (size_t)(s * KCODES + best) * DDIM + q * 32;
            float cp = 0.0f;
            #pragma unroll
            for (int k = 0; k < 8; ++k) {
                float4 a = *(const float4*)(Eb + 4 * k);
                r[4*k]   -= a.x; r[4*k+1] -= a.y; r[4*k+2] -= a.z; r[4*k+3] -= a.w;
                cp += r[4*k]*r[4*k] + r[4*k+1]*r[4*k+1] + r[4*k+2]*r[4*k+2] + r[4*k+3]*r[4*k+3];
            }
            if (s == 0) commit_part = cp;
        }

        __syncthreads();   // everyone done with cand/besti2 and B-frag reads
        // ---- rebuild rh: residual fp16 (or y = x - r after last stage) ----
        if (s < NVQ - 1) {
            #pragma unroll
            for (int k = 0; k < 4; ++k) {
                f16x8 h;
                #pragma unroll
                for (int m = 0; m < 8; ++m) h[m] = (f16)r[8*k+m];
                *(f16x8*)&rh[swz(p_own, q * 4 + k)] = h;
            }
        } else {
            const float* xs = x + (size_t)(p0 + p_own) * DDIM + q * 32;
            #pragma unroll
            for (int k = 0; k < 4; ++k) {
                float4 a = *(const float4*)(xs + 8 * k);
                float4 b = *(const float4*)(xs + 8 * k + 4);
                f16x8 h;
                h[0]=(f16)(a.x - r[8*k+0]); h[1]=(f16)(a.y - r[8*k+1]);
                h[2]=(f16)(a.z - r[8*k+2]); h[3]=(f16)(a.w - r[8*k+3]);
                h[4]=(f16)(b.x - r[8*k+4]); h[5]=(f16)(b.y - r[8*k+5]);
                h[6]=(f16)(b.z - r[8*k+6]); h[7]=(f16)(b.w - r[8*k+7]);
                *(f16x8*)&rh[swz(p_own, q * 4 + k)] = h;
            }
        }
        __syncthreads();
    }

    // ---- final linear: out = y @ W^T + b (A = W rows, 2 chunks of 64) ----
    {
        f16x8 Bf[4][4];
        #pragma unroll
        for (int j = 0; j < 4; ++j)
            #pragma unroll
            for (int ks = 0; ks < 4; ++ks)
                Bf[j][ks] = *(const f16x8*)&rh[swz(16 * j + li, ks * 4 + g)];

        for (int ch = 0; ch < 2; ++ch) {
            __syncthreads();
            {
                const float* src = W + (size_t)ch * CHUNKC * DDIM;
                #pragma unroll
                for (int it = 0; it < 4; ++it) {
                    int u = tid + it * BLOCKT; int row = u >> 4, grp = u & 15;
                    const float* sp = src + row * DDIM + grp * 8;
                    float4 a = *(const float4*)sp;
                    float4 b = *(const float4*)(sp + 4);
                    *(f16x8*)&e_lds[swz(row, grp)] = cvt8(a, b);
                }
                if (tid < CHUNKC) cn[tid] = bias[ch * CHUNKC + tid];
            }
            __syncthreads();

            float4 bn = *(const float4*)&cn[16 * wid + 4 * g];
            f32x4 acc[4];
            #pragma unroll
            for (int j = 0; j < 4; ++j) {
                acc[j][0] = bn.x; acc[j][1] = bn.y; acc[j][2] = bn.z; acc[j][3] = bn.w;
            }
            #pragma unroll
            for (int ks = 0; ks < 4; ++ks) {
                f16x8 A = *(const f16x8*)&e_lds[swz(16 * wid + li, ks * 4 + g)];
                #pragma unroll
                for (int j = 0; j < 4; ++j)
                    acc[j] = __builtin_amdgcn_mfma_f32_16x16x32_f16(A, Bf[j][ks], acc[j], 0, 0, 0);
            }

            int obase = ch * CHUNKC + 16 * wid + 4 * g;
            #pragma unroll
            for (int j = 0; j < 4; ++j) {
                int p = 16 * j + li;
                float4 o;
                o.x = acc[j][0]; o.y = acc[j][1]; o.z = acc[j][2]; o.w = acc[j][3];
                *(float4*)(out + (size_t)(p0 + p) * DDIM + obase) = o;
            }
        }
    }

    // ---- commit loss: wave shuffle-reduce, then 4 partials + atomic ----
    {
        float cp = commit_part;
        #pragma unroll
        for (int m = 1; m <= 32; m <<= 1) cp += __shfl_xor(cp, m);
        __syncthreads();                 // cand free for reuse as scratch
        float* wsum = (float*)cand;
        if (lane == 0) wsum[wid] = cp;
        __syncthreads();
        if (tid == 0) {
            float t = (wsum[0] + wsum[1]) + (wsum[2] + wsum[3]);
            atomicAdd(out + (size_t)NPTS * DDIM + NPTS,
                      t * (1.0f / ((float)NPTS * (float)DDIM)));
        }
    }
}

// ---------------------------------------------------------------------------
extern "C" void kernel_launch(void* const* d_in, const int* in_sizes, int n_in,
                              void* d_out, int out_size, void* d_ws, size_t ws_size,
                              hipStream_t stream) {
    const float* x    = (const float*)d_in[0];
    const float* cb   = (const float*)d_in[1];
    const float* linw = (const float*)d_in[2];
    const float* linb = (const float*)d_in[3];
    float* out  = (float*)d_out;
    float* norms = (float*)d_ws;                       // 3072 floats
    f16*  cb16  = (f16*)((char*)d_ws + 16384);         // 786432 B fp16 codebook
    const size_t need = 16384 + (size_t)NVQ * KCODES * DDIM * 2;

    zero_commit_kernel<<<1, 1, 0, stream>>>(out + (size_t)NPTS * DDIM + NPTS);
    norms_kernel<<<NVQ * KCODES, 64, 0, stream>>>(cb, norms);

    if (ws_size >= need) {
        preconv_kernel<<<(NVQ * KCODES * DDIM) / (256 * 8), 256, 0, stream>>>(cb, cb16);
        rvq_kernel<true><<<NPTS / TM, BLOCKT, 0, stream>>>(x, cb, cb16, linw, linb, norms, out);
    } else {
        rvq_kernel<false><<<NPTS / TM, BLOCKT, 0, stream>>>(x, cb, cb16, linw, linb, norms, out);
    }
}

// Round 5
// 843.054 us; speedup vs baseline: 3.5475x; 1.5445x over previous
//
#include <hip/hip_runtime.h>
#include <float.h>

typedef _Float16 f16;
typedef f16 f16x8 __attribute__((ext_vector_type(8)));
typedef float f32x4 __attribute__((ext_vector_type(4)));
typedef unsigned int u32;

#define NPTS 262144
#define DDIM 128
#define NVQ 6
#define KCODES 512
#define TM 64          // points per block
#define BLOCKT 256
#define RPITCH 132     // padded fp32 pitch: bank quad = (row + granule) % 8

__device__ __forceinline__ f16x8 cvt8(float4 a, float4 b) {
    f16x8 h;
    h[0] = (f16)a.x; h[1] = (f16)a.y; h[2] = (f16)a.z; h[3] = (f16)a.w;
    h[4] = (f16)b.x; h[5] = (f16)b.y; h[6] = (f16)b.z; h[7] = (f16)b.w;
    return h;
}

// ---------------------------------------------------------------------------
__global__ void zero_commit_kernel(float* p) { *p = 0.0f; }

// norms[row] = ||E_row||^2 (exact, for rescue); ascore[row] = 512 - 0.5*||E||^2
// (offset keeps all approx scores strictly positive -> f64 key ordering valid)
__global__ void norms_kernel(const float* __restrict__ cb, float* __restrict__ norms,
                             float* __restrict__ ascore) {
    int row = blockIdx.x;
    int lane = threadIdx.x;
    const float* r = cb + (size_t)row * DDIM;
    float2 v = *(const float2*)(r + lane * 2);
    float s = v.x * v.x + v.y * v.y;
    #pragma unroll
    for (int m = 32; m >= 1; m >>= 1) s += __shfl_xor(s, m);
    if (lane == 0) { norms[row] = s; ascore[row] = 512.0f - 0.5f * s; }
}

__global__ void preconv_kernel(const float* __restrict__ cb, f16* __restrict__ cb16) {
    size_t base = ((size_t)blockIdx.x * 256 + threadIdx.x) * 8;
    float4 a = *(const float4*)(cb + base);
    float4 b = *(const float4*)(cb + base + 4);
    *(f16x8*)(cb16 + base) = cvt8(a, b);
}

// ---------------------------------------------------------------------------
// Residual VQ: residual fp32 lives in LDS; codebook A-fragments stream from
// global (L2-resident); top-2 tracked as packed f64 keys (score|invcode).
template<bool PRE>
__global__ __launch_bounds__(BLOCKT, 2)
void rvq_kernel(const float* __restrict__ x, const float* __restrict__ cb,
                const f16* __restrict__ cb16, const float* __restrict__ W,
                const float* __restrict__ bias, const float* __restrict__ norms,
                const float* __restrict__ ascore, float* __restrict__ out) {
    __shared__ float   r32[TM][RPITCH];   // 33792 B: residual (later y), fp32
    __shared__ double2 cand[4][TM];       // 4096 B: per-wave top2 keys per point
    __shared__ uint2   besti2[TM];        // 512 B

    const int tid  = threadIdx.x;
    const int wid  = tid >> 6;
    const int lane = tid & 63;
    const int g    = lane >> 4;      // k-group 0..3
    const int li   = lane & 15;      // row/col within 16-tile
    const int p_own = tid >> 2;      // owned point 0..63
    const int q     = tid & 3;       // owned d-quarter
    const int p0    = blockIdx.x * TM;

    // ---- x -> r32 ----
    {
        const float* xs = x + (size_t)(p0 + p_own) * DDIM + q * 32;
        #pragma unroll
        for (int k = 0; k < 8; ++k)
            *(float4*)&r32[p_own][q * 32 + 4 * k] = *(const float4*)(xs + 4 * k);
    }
    __syncthreads();

    float commit_part = 0.0f;

    #pragma unroll 1
    for (int s = 0; s < NVQ; ++s) {
        // ---- B fragments: fp32 LDS -> fp16 regs, reused across all 512 codes ----
        f16x8 Bf[4][4];
        #pragma unroll
        for (int j = 0; j < 4; ++j)
            #pragma unroll
            for (int ks = 0; ks < 4; ++ks) {
                const float* bp = &r32[16 * j + li][(ks * 4 + g) * 8];
                Bf[j][ks] = cvt8(*(const float4*)bp, *(const float4*)(bp + 4));
            }

        double k1[4], k2[4];
        #pragma unroll
        for (int j = 0; j < 4; ++j) { k1[j] = 0.0; k2[j] = 0.0; }
        const int invbase = 511 - 16 * wid - 4 * g;

        const f16*   Ab   = cb16 + ((size_t)s * KCODES + 16 * wid + li) * DDIM + g * 8;
        const float* Ab32 = cb   + ((size_t)s * KCODES + 16 * wid + li) * DDIM + g * 8;
        const float* asb  = ascore + s * KCODES + 16 * wid + 4 * g;

        #pragma unroll 2
        for (int ch = 0; ch < 8; ++ch) {
            float4 as4 = *(const float4*)(asb + ch * 64);
            f32x4 acc[4];
            #pragma unroll
            for (int j = 0; j < 4; ++j) acc[j] = (f32x4)0.0f;

            #pragma unroll
            for (int ks = 0; ks < 4; ++ks) {
                f16x8 Af;
                if (PRE) {
                    Af = *(const f16x8*)(Ab + (size_t)ch * 64 * DDIM + ks * 32);
                } else {
                    const float* ap = Ab32 + (size_t)ch * 64 * DDIM + ks * 32;
                    Af = cvt8(*(const float4*)ap, *(const float4*)(ap + 4));
                }
                #pragma unroll
                for (int j = 0; j < 4; ++j)
                    acc[j] = __builtin_amdgcn_mfma_f32_16x16x32_f16(Af, Bf[j][ks], acc[j], 0, 0, 0);
            }

            const int invc = invbase - ch * 64;
            #pragma unroll
            for (int j = 0; j < 4; ++j) {
                #pragma unroll
                for (int reg = 0; reg < 4; ++reg) {
                    float sc = acc[j][reg] +
                        ((reg == 0) ? as4.x : (reg == 1) ? as4.y : (reg == 2) ? as4.z : as4.w);
                    double kk = __hiloint2double(__float_as_int(sc), invc - reg);
                    double lo = fmin(k1[j], kk);
                    k1[j] = fmax(k1[j], kk);
                    k2[j] = fmax(k2[j], lo);
                }
            }
        }

        // ---- in-wave top-2 merge across k-groups (lanes xor 16, 32) ----
        #pragma unroll
        for (int m = 16; m <= 32; m <<= 1) {
            #pragma unroll
            for (int j = 0; j < 4; ++j) {
                double o1 = __shfl_xor(k1[j], m);
                double o2 = __shfl_xor(k2[j], m);
                double lo = fmin(k1[j], o1);
                k1[j] = fmax(k1[j], o1);
                k2[j] = fmax(fmax(k2[j], o2), lo);
            }
        }
        if (lane < 16) {
            #pragma unroll
            for (int j = 0; j < 4; ++j)
                cand[wid][16 * j + li] = make_double2(k1[j], k2[j]);
        }
        __syncthreads();

        // ---- cross-wave merge + decode ----
        if (tid < TM) {
            double2 v0 = cand[0][tid];
            double a1 = v0.x, a2 = v0.y;
            #pragma unroll
            for (int w = 1; w < 4; ++w) {
                double2 vv = cand[w][tid];
                double lo = fmin(a1, vv.x);
                a1 = fmax(a1, vv.x);
                a2 = fmax(fmax(a2, vv.y), lo);
            }
            u32 c1 = 511u - (u32)__double2loint(a1);
            u32 c2 = 511u - (u32)__double2loint(a2);
            besti2[tid] = make_uint2(c1, c2);
        }
        __syncthreads();

        // ---- exact fp32 rescue on top-2 ----
        uint2 bc = besti2[p_own];
        int c1 = (int)bc.x, c2 = (int)bc.y;
        float rq[32];
        #pragma unroll
        for (int k = 0; k < 8; ++k) {
            float4 rv = *(const float4*)&r32[p_own][q * 32 + 4 * k];
            rq[4*k] = rv.x; rq[4*k+1] = rv.y; rq[4*k+2] = rv.z; rq[4*k+3] = rv.w;
        }
        const float* E1 = cb + (size_t)(s * KCODES + c1) * DDIM + q * 32;
        const float* E2 = cb + (size_t)(s * KCODES + c2) * DDIM + q * 32;
        float dot1 = 0.0f, dot2 = 0.0f;
        #pragma unroll
        for (int k = 0; k < 8; ++k) {
            float4 a = *(const float4*)(E1 + 4 * k);
            dot1 += a.x * rq[4*k] + a.y * rq[4*k+1] + a.z * rq[4*k+2] + a.w * rq[4*k+3];
        }
        #pragma unroll
        for (int k = 0; k < 8; ++k) {
            float4 a = *(const float4*)(E2 + 4 * k);
            dot2 += a.x * rq[4*k] + a.y * rq[4*k+1] + a.z * rq[4*k+2] + a.w * rq[4*k+3];
        }
        dot1 += __shfl_xor(dot1, 1); dot1 += __shfl_xor(dot1, 2);
        dot2 += __shfl_xor(dot2, 1); dot2 += __shfl_xor(dot2, 2);
        float d1e = fmaf(-2.0f, dot1, norms[s * KCODES + c1]);
        float d2e = fmaf(-2.0f, dot2, norms[s * KCODES + c2]);
        int best = (d2e < d1e || (d2e == d1e && c2 < c1)) ? c2 : c1;

        if (s == 0 && q == 0)
            out[(size_t)NPTS * DDIM + p0 + p_own] = (float)best;

        // ---- residual update (exact fp32) ----
        {
            const float* Eb = cb + (size_t)(s * KCODES + best) * DDIM + q * 32;
            float cp = 0.0f;
            #pragma unroll
            for (int k = 0; k < 8; ++k) {
                float4 e = *(const float4*)(Eb + 4 * k);
                float r0 = rq[4*k]   - e.x;
                float r1 = rq[4*k+1] - e.y;
                float r2 = rq[4*k+2] - e.z;
                float r3 = rq[4*k+3] - e.w;
                *(float4*)&r32[p_own][q * 32 + 4 * k] = make_float4(r0, r1, r2, r3);
                cp += r0 * r0 + r1 * r1 + r2 * r2 + r3 * r3;
            }
            if (s == 0) commit_part = cp;
        }
        __syncthreads();
    }

    // ---- y = x - r_final (into r32) ----
    {
        const float* xs = x + (size_t)(p0 + p_own) * DDIM + q * 32;
        #pragma unroll
        for (int k = 0; k < 8; ++k) {
            float4 xv = *(const float4*)(xs + 4 * k);
            float4 rv = *(const float4*)&r32[p_own][q * 32 + 4 * k];
            *(float4*)&r32[p_own][q * 32 + 4 * k] =
                make_float4(xv.x - rv.x, xv.y - rv.y, xv.z - rv.z, xv.w - rv.w);
        }
    }
    __syncthreads();

    // ---- final linear: out = y @ W^T + b (A = W rows from global, cvt) ----
    {
        f16x8 Yf[4][4];
        #pragma unroll
        for (int j = 0; j < 4; ++j)
            #pragma unroll
            for (int ks = 0; ks < 4; ++ks) {
                const float* bp = &r32[16 * j + li][(ks * 4 + g) * 8];
                Yf[j][ks] = cvt8(*(const float4*)bp, *(const float4*)(bp + 4));
            }

        #pragma unroll 1
        for (int ch = 0; ch < 2; ++ch) {
            float4 b4 = *(const float4*)(bias + ch * 64 + 16 * wid + 4 * g);
            f32x4 acc[4];
            #pragma unroll
            for (int j = 0; j < 4; ++j) {
                acc[j][0] = b4.x; acc[j][1] = b4.y; acc[j][2] = b4.z; acc[j][3] = b4.w;
            }
            #pragma unroll
            for (int ks = 0; ks < 4; ++ks) {
                const float* wp = W + (size_t)(ch * 64 + 16 * wid + li) * DDIM + ks * 32 + g * 8;
                f16x8 Af = cvt8(*(const float4*)wp, *(const float4*)(wp + 4));
                #pragma unroll
                for (int j = 0; j < 4; ++j)
                    acc[j] = __builtin_amdgcn_mfma_f32_16x16x32_f16(Af, Yf[j][ks], acc[j], 0, 0, 0);
            }
            int obase = ch * 64 + 16 * wid + 4 * g;
            #pragma unroll
            for (int j = 0; j < 4; ++j)
                *(float4*)(out + (size_t)(p0 + 16 * j + li) * DDIM + obase) =
                    make_float4(acc[j][0], acc[j][1], acc[j][2], acc[j][3]);
        }
    }

    // ---- commit loss: wave shuffle-reduce + block atomic ----
    {
        float cp = commit_part;
        #pragma unroll
        for (int m = 1; m <= 32; m <<= 1) cp += __shfl_xor(cp, m);
        __syncthreads();
        float* wsum = (float*)cand;
        if (lane == 0) wsum[wid] = cp;
        __syncthreads();
        if (tid == 0) {
            float t = (wsum[0] + wsum[1]) + (wsum[2] + wsum[3]);
            atomicAdd(out + (size_t)NPTS * DDIM + NPTS,
                      t * (1.0f / ((float)NPTS * (float)DDIM)));
        }
    }
}

// ---------------------------------------------------------------------------
extern "C" void kernel_launch(void* const* d_in, const int* in_sizes, int n_in,
                              void* d_out, int out_size, void* d_ws, size_t ws_size,
                              hipStream_t stream) {
    const float* x    = (const float*)d_in[0];
    const float* cb   = (const float*)d_in[1];
    const float* linw = (const float*)d_in[2];
    const float* linb = (const float*)d_in[3];
    float* out    = (float*)d_out;
    float* norms  = (float*)d_ws;                        // 3072 f
    float* ascore = norms + 4096;                        // 3072 f
    f16*   cb16   = (f16*)((char*)d_ws + 32768);         // 786432 B
    const size_t need = 32768 + (size_t)NVQ * KCODES * DDIM * 2;

    zero_commit_kernel<<<1, 1, 0, stream>>>(out + (size_t)NPTS * DDIM + NPTS);
    norms_kernel<<<NVQ * KCODES, 64, 0, stream>>>(cb, norms, ascore);

    if (ws_size >= need) {
        preconv_kernel<<<(NVQ * KCODES * DDIM) / (256 * 8), 256, 0, stream>>>(cb, cb16);
        rvq_kernel<true><<<NPTS / TM, BLOCKT, 0, stream>>>(x, cb, cb16, linw, linb,
                                                           norms, ascore, out);
    } else {
        rvq_kernel<false><<<NPTS / TM, BLOCKT, 0, stream>>>(x, cb, cb16, linw, linb,
                                                            norms, ascore, out);
    }
}

// Round 6
// 774.129 us; speedup vs baseline: 3.8633x; 1.0890x over previous
//
#include <hip/hip_runtime.h>
#include <float.h>

typedef _Float16 f16;
typedef f16 f16x8 __attribute__((ext_vector_type(8)));
typedef float f32x4 __attribute__((ext_vector_type(4)));
typedef unsigned int u32;

#define NPTS 262144
#define DDIM 128
#define NVQ 6
#define KCODES 512
#define TM 64
#define BLOCKT 256

__device__ __forceinline__ int swz(int row, int grp) {
    return row * DDIM + ((grp ^ (row & 7)) << 3);
}
__device__ __forceinline__ u32 umin32(u32 a, u32 b) { return a < b ? a : b; }
__device__ __forceinline__ u32 umax32(u32 a, u32 b) { return a > b ? a : b; }

__device__ __forceinline__ f16x8 cvt8(float4 a, float4 b) {
    f16x8 h;
    h[0] = (f16)a.x; h[1] = (f16)a.y; h[2] = (f16)a.z; h[3] = (f16)a.w;
    h[4] = (f16)b.x; h[5] = (f16)b.y; h[6] = (f16)b.z; h[7] = (f16)b.w;
    return h;
}

// ---------------------------------------------------------------------------
__global__ void zero_commit_kernel(float* p) { *p = 0.0f; }

// norms[row] = ||E||^2 exact; ascore[row] = 512 - 0.5*||E||^2 (keeps approx
// scores strictly positive so uint ordering of float bits is valid)
__global__ void norms_kernel(const float* __restrict__ cb, float* __restrict__ norms,
                             float* __restrict__ ascore) {
    int row = blockIdx.x;
    int lane = threadIdx.x;
    const float* r = cb + (size_t)row * DDIM;
    float2 v = *(const float2*)(r + lane * 2);
    float s = v.x * v.x + v.y * v.y;
    #pragma unroll
    for (int m = 32; m >= 1; m >>= 1) s += __shfl_xor(s, m);
    if (lane == 0) { norms[row] = s; ascore[row] = 512.0f - 0.5f * s; }
}

__global__ void preconv_kernel(const float* __restrict__ cb, f16* __restrict__ cb16) {
    size_t base = ((size_t)blockIdx.x * 256 + threadIdx.x) * 8;
    float4 a = *(const float4*)(cb + base);
    float4 b = *(const float4*)(cb + base + 4);
    *(f16x8*)(cb16 + base) = cvt8(a, b);
}

// ---------------------------------------------------------------------------
// Residual VQ: residual fp32 in REGISTERS (spill-free at 256,2 — r2/r5
// precedent); fp16 swizzled rh in LDS only for MFMA B-fragments; codebook A
// streamed from global fp16 (L2-resident); top-2 as packed u32 keys.
template<bool PRE>
__global__ __launch_bounds__(BLOCKT, 2)
void rvq_kernel(const float* __restrict__ x, const float* __restrict__ cb,
                const f16* __restrict__ cb16, const float* __restrict__ W,
                const float* __restrict__ bias, const float* __restrict__ norms,
                const float* __restrict__ ascore, float* __restrict__ out) {
    __shared__ f16   rh[TM * DDIM];    // 16 KB residual/y fp16, swizzled
    __shared__ uint2 cand[4][TM];      // 2 KB  per-wave top2 keys per point

    const int tid  = threadIdx.x;
    const int wid  = tid >> 6;
    const int lane = tid & 63;
    const int g    = lane >> 4;      // k-group 0..3
    const int li   = lane & 15;      // row/col within 16-tile
    const int p_own = tid >> 2;      // owned point 0..63
    const int q     = tid & 3;       // owned d-quarter
    const int p0    = blockIdx.x * TM;

    // ---- x -> r (regs) and rh (fp16 LDS) ----
    float r[32];
    {
        const float* xs = x + (size_t)(p0 + p_own) * DDIM + q * 32;
        #pragma unroll
        for (int k = 0; k < 8; ++k) {
            float4 v = *(const float4*)(xs + 4 * k);
            r[4*k] = v.x; r[4*k+1] = v.y; r[4*k+2] = v.z; r[4*k+3] = v.w;
        }
    }
    #pragma unroll
    for (int k = 0; k < 4; ++k) {
        f16x8 h;
        #pragma unroll
        for (int m = 0; m < 8; ++m) h[m] = (f16)r[8*k+m];
        *(f16x8*)&rh[swz(p_own, q * 4 + k)] = h;
    }
    __syncthreads();

    float commit_part = 0.0f;

    #pragma unroll 1
    for (int s = 0; s < NVQ; ++s) {
        // ---- B fragments from rh (one b128 each), reused over all 512 codes ----
        f16x8 Bf[4][4];
        #pragma unroll
        for (int j = 0; j < 4; ++j)
            #pragma unroll
            for (int ks = 0; ks < 4; ++ks)
                Bf[j][ks] = *(const f16x8*)&rh[swz(16 * j + li, ks * 4 + g)];

        u32 k1[4], k2[4];
        #pragma unroll
        for (int j = 0; j < 4; ++j) { k1[j] = 0u; k2[j] = 0u; }

        const f16*   Ab   = cb16 + ((size_t)s * KCODES + 16 * wid + li) * DDIM + g * 8;
        const float* Ab32 = cb   + ((size_t)s * KCODES + 16 * wid + li) * DDIM + g * 8;
        const float* asb  = ascore + s * KCODES + 16 * wid + 4 * g;

        #pragma unroll 2
        for (int ch = 0; ch < 8; ++ch) {
            float4 as4 = *(const float4*)(asb + ch * 64);
            f32x4 acc[4];
            #pragma unroll
            for (int j = 0; j < 4; ++j) acc[j] = (f32x4)0.0f;

            #pragma unroll
            for (int ks = 0; ks < 4; ++ks) {
                f16x8 Af;
                if (PRE) {
                    Af = *(const f16x8*)(Ab + (size_t)ch * 64 * DDIM + ks * 32);
                } else {
                    const float* ap = Ab32 + (size_t)ch * 64 * DDIM + ks * 32;
                    Af = cvt8(*(const float4*)ap, *(const float4*)(ap + 4));
                }
                #pragma unroll
                for (int j = 0; j < 4; ++j)
                    acc[j] = __builtin_amdgcn_mfma_f32_16x16x32_f16(Af, Bf[j][ks], acc[j], 0, 0, 0);
            }

            const int invc = 511 - (ch * 64 + 16 * wid + 4 * g);
            #pragma unroll
            for (int j = 0; j < 4; ++j) {
                #pragma unroll
                for (int reg = 0; reg < 4; ++reg) {
                    float sc = acc[j][reg] +
                        ((reg == 0) ? as4.x : (reg == 1) ? as4.y : (reg == 2) ? as4.z : as4.w);
                    u32 key = (__float_as_uint(sc) & 0xFFFFFE00u) | (u32)(invc - reg);
                    u32 lo = umin32(k1[j], key);
                    k1[j] = umax32(k1[j], key);
                    k2[j] = umax32(k2[j], lo);
                }
            }
        }

        // ---- in-wave top-2 butterfly across k-groups (lanes xor 16, 32) ----
        #pragma unroll
        for (int m = 16; m <= 32; m <<= 1) {
            #pragma unroll
            for (int j = 0; j < 4; ++j) {
                u32 o1 = (u32)__shfl_xor((int)k1[j], m);
                u32 o2 = (u32)__shfl_xor((int)k2[j], m);
                u32 lo = umin32(k1[j], o1);
                k1[j] = umax32(k1[j], o1);
                k2[j] = umax32(umax32(k2[j], o2), lo);
            }
        }
        if (lane < 16) {
            #pragma unroll
            for (int j = 0; j < 4; ++j)
                cand[wid][16 * j + li] = make_uint2(k1[j], k2[j]);
        }
        __syncthreads();

        // ---- cross-wave merge, redundantly in every thread (no 2nd barrier) ----
        uint2 v0 = cand[0][p_own];
        u32 m1 = v0.x, m2 = v0.y;
        #pragma unroll
        for (int w = 1; w < 4; ++w) {
            uint2 vv = cand[w][p_own];
            u32 lo = umin32(m1, vv.x);
            m1 = umax32(m1, vv.x);
            m2 = umax32(umax32(m2, vv.y), lo);
        }
        int c1 = 511 - (int)(m1 & 0x1FFu);
        int c2 = 511 - (int)(m2 & 0x1FFu);

        // ---- exact fp32 rescue on top-2 (registers only) ----
        const float* E1 = cb + (size_t)(s * KCODES + c1) * DDIM + q * 32;
        const float* E2 = cb + (size_t)(s * KCODES + c2) * DDIM + q * 32;
        float dot1 = 0.0f, dot2 = 0.0f;
        #pragma unroll
        for (int k = 0; k < 8; ++k) {
            float4 a = *(const float4*)(E1 + 4 * k);
            dot1 += a.x * r[4*k] + a.y * r[4*k+1] + a.z * r[4*k+2] + a.w * r[4*k+3];
        }
        #pragma unroll
        for (int k = 0; k < 8; ++k) {
            float4 a = *(const float4*)(E2 + 4 * k);
            dot2 += a.x * r[4*k] + a.y * r[4*k+1] + a.z * r[4*k+2] + a.w * r[4*k+3];
        }
        dot1 += __shfl_xor(dot1, 1); dot1 += __shfl_xor(dot1, 2);
        dot2 += __shfl_xor(dot2, 1); dot2 += __shfl_xor(dot2, 2);
        float d1e = fmaf(-2.0f, dot1, norms[s * KCODES + c1]);
        float d2e = fmaf(-2.0f, dot2, norms[s * KCODES + c2]);
        int best = (d2e < d1e || (d2e == d1e && c2 < c1)) ? c2 : c1;

        if (s == 0 && q == 0)
            out[(size_t)NPTS * DDIM + p0 + p_own] = (float)best;

        // ---- exact residual update (regs) + rh rewrite for next stage ----
        {
            const float* Eb = cb + (size_t)(s * KCODES + best) * DDIM + q * 32;
            float cp = 0.0f;
            #pragma unroll
            for (int k = 0; k < 8; ++k) {
                float4 e = *(const float4*)(Eb + 4 * k);
                r[4*k]   -= e.x; r[4*k+1] -= e.y; r[4*k+2] -= e.z; r[4*k+3] -= e.w;
                cp += r[4*k]*r[4*k] + r[4*k+1]*r[4*k+1] + r[4*k+2]*r[4*k+2] + r[4*k+3]*r[4*k+3];
            }
            if (s == 0) commit_part = cp;
        }
        if (s < NVQ - 1) {
            #pragma unroll
            for (int k = 0; k < 4; ++k) {
                f16x8 h;
                #pragma unroll
                for (int m = 0; m < 8; ++m) h[m] = (f16)r[8*k+m];
                *(f16x8*)&rh[swz(p_own, q * 4 + k)] = h;
            }
        }
        __syncthreads();
    }

    // ---- y = x - r_final -> rh ----
    {
        const float* xs = x + (size_t)(p0 + p_own) * DDIM + q * 32;
        #pragma unroll
        for (int k = 0; k < 4; ++k) {
            float4 a = *(const float4*)(xs + 8 * k);
            float4 b = *(const float4*)(xs + 8 * k + 4);
            f16x8 h;
            h[0]=(f16)(a.x - r[8*k+0]); h[1]=(f16)(a.y - r[8*k+1]);
            h[2]=(f16)(a.z - r[8*k+2]); h[3]=(f16)(a.w - r[8*k+3]);
            h[4]=(f16)(b.x - r[8*k+4]); h[5]=(f16)(b.y - r[8*k+5]);
            h[6]=(f16)(b.z - r[8*k+6]); h[7]=(f16)(b.w - r[8*k+7]);
            *(f16x8*)&rh[swz(p_own, q * 4 + k)] = h;
        }
    }
    __syncthreads();

    // ---- final linear: out = y @ W^T + b (W rows streamed from global) ----
    {
        f16x8 Yf[4][4];
        #pragma unroll
        for (int j = 0; j < 4; ++j)
            #pragma unroll
            for (int ks = 0; ks < 4; ++ks)
                Yf[j][ks] = *(const f16x8*)&rh[swz(16 * j + li, ks * 4 + g)];

        #pragma unroll 1
        for (int ch = 0; ch < 2; ++ch) {
            float4 b4 = *(const float4*)(bias + ch * 64 + 16 * wid + 4 * g);
            f32x4 acc[4];
            #pragma unroll
            for (int j = 0; j < 4; ++j) {
                acc[j][0] = b4.x; acc[j][1] = b4.y; acc[j][2] = b4.z; acc[j][3] = b4.w;
            }
            #pragma unroll
            for (int ks = 0; ks < 4; ++ks) {
                const float* wp = W + (size_t)(ch * 64 + 16 * wid + li) * DDIM + ks * 32 + g * 8;
                f16x8 Af = cvt8(*(const float4*)wp, *(const float4*)(wp + 4));
                #pragma unroll
                for (int j = 0; j < 4; ++j)
                    acc[j] = __builtin_amdgcn_mfma_f32_16x16x32_f16(Af, Yf[j][ks], acc[j], 0, 0, 0);
            }
            int obase = ch * 64 + 16 * wid + 4 * g;
            #pragma unroll
            for (int j = 0; j < 4; ++j)
                *(float4*)(out + (size_t)(p0 + 16 * j + li) * DDIM + obase) =
                    make_float4(acc[j][0], acc[j][1], acc[j][2], acc[j][3]);
        }
    }

    // ---- commit loss: wave shuffle-reduce + block atomic ----
    {
        float cp = commit_part;
        #pragma unroll
        for (int m = 1; m <= 32; m <<= 1) cp += __shfl_xor(cp, m);
        __syncthreads();
        float* wsum = (float*)cand;
        if (lane == 0) wsum[wid] = cp;
        __syncthreads();
        if (tid == 0) {
            float t = (wsum[0] + wsum[1]) + (wsum[2] + wsum[3]);
            atomicAdd(out + (size_t)NPTS * DDIM + NPTS,
                      t * (1.0f / ((float)NPTS * (float)DDIM)));
        }
    }
}

// ---------------------------------------------------------------------------
extern "C" void kernel_launch(void* const* d_in, const int* in_sizes, int n_in,
                              void* d_out, int out_size, void* d_ws, size_t ws_size,
                              hipStream_t stream) {
    const float* x    = (const float*)d_in[0];
    const float* cb   = (const float*)d_in[1];
    const float* linw = (const float*)d_in[2];
    const float* linb = (const float*)d_in[3];
    float* out    = (float*)d_out;
    float* norms  = (float*)d_ws;                        // 3072 f
    float* ascore = norms + 4096;                        // 3072 f
    f16*   cb16   = (f16*)((char*)d_ws + 32768);         // 786432 B
    const size_t need = 32768 + (size_t)NVQ * KCODES * DDIM * 2;

    zero_commit_kernel<<<1, 1, 0, stream>>>(out + (size_t)NPTS * DDIM + NPTS);
    norms_kernel<<<NVQ * KCODES, 64, 0, stream>>>(cb, norms, ascore);

    if (ws_size >= need) {
        preconv_kernel<<<(NVQ * KCODES * DDIM) / (256 * 8), 256, 0, stream>>>(cb, cb16);
        rvq_kernel<true><<<NPTS / TM, BLOCKT, 0, stream>>>(x, cb, cb16, linw, linb,
                                                           norms, ascore, out);
    } else {
        rvq_kernel<false><<<NPTS / TM, BLOCKT, 0, stream>>>(x, cb, cb16, linw, linb,
                                                            norms, ascore, out);
    }
}